// Round 1
// baseline (614.441 us; speedup 1.0000x reference)
//
#include <hip/hip_runtime.h>
#include <math.h>

// WheelMultiheadAttention on MI355X (gfx950)
// B=2 T=2048 C=1024 H=16 D=64. Outputs: out [2,2048,1024] f32 then weights [2,16,2048,2048] f32.

typedef __bf16 bf16;
typedef __bf16 bf16x4 __attribute__((ext_vector_type(4)));
typedef __bf16 bf16x8 __attribute__((ext_vector_type(8)));
typedef float  f32x4  __attribute__((ext_vector_type(4)));

#define MFMA16(a, b, c) __builtin_amdgcn_mfma_f32_16x16x32_bf16((a), (b), (c), 0, 0, 0)

__device__ __forceinline__ void gload16(void* lds, const void* g) {
  __builtin_amdgcn_global_load_lds((__attribute__((address_space(1))) void*)(g),
                                   (__attribute__((address_space(3))) void*)(lds),
                                   16, 0, 0);
}

// ---------------- f32 -> bf16 hi/lo split ----------------
__global__ __launch_bounds__(256) void conv_split(const float* __restrict__ x,
                                                  bf16* __restrict__ hi,
                                                  bf16* __restrict__ lo, int n) {
  int i = (blockIdx.x * 256 + threadIdx.x) * 4;
  if (i >= n) return;
  f32x4 v = *(const f32x4*)(x + i);
  bf16x4 h4, l4;
#pragma unroll
  for (int r = 0; r < 4; ++r) {
    float f = v[r];
    bf16 h = (bf16)f;
    h4[r] = h;
    l4[r] = (bf16)(f - (float)h);
  }
  *(bf16x4*)(hi + i) = h4;
  *(bf16x4*)(lo + i) = l4;
}

// ---------------- shared GEMM helpers (128x128 tile, K-step 32, stride-1024 sources) ----
// LDS tile [128 rows][32 cols] bf16, 16B chunks XOR-swizzled: pos = chunk ^ ((row>>1)&3)
// (both-sides swizzle: pre-swizzled global source + swizzled read -> 2-way banks = free)
__device__ __forceinline__ void stage_tile(bf16* lds, const bf16* g, int row0, int kc, int tid) {
#pragma unroll
  for (int j = 0; j < 2; ++j) {
    int chunk = j * 256 + tid;
    int r = chunk >> 2, cpos = chunk & 3;
    int csrc = cpos ^ ((r >> 1) & 3);
    gload16((char*)lds + chunk * 16,
            (const char*)(g + (size_t)(row0 + r) * 1024 + kc) + csrc * 16);
  }
}

__device__ __forceinline__ bf16x8 frag_ld(const bf16* lds, int row, int g) {
  int pos = g ^ ((row >> 1) & 3);
  return *(const bf16x8*)((const char*)lds + row * 64 + pos * 16);
}

// ---------------- transposed-orientation GEMM:  Y[o][t] = sum_c W[o][c] * X[t][c] (+bias[o])
// MODE 0: split inputs (3 MFMAs), write (y*scale) split hi/lo to [B,H,T,D]
// MODE 2: plain, write f32 to Out[t][o] (final output projection)
template <int MODE>
__global__ __launch_bounds__(256) void gemm_t(const bf16* __restrict__ Ah, const bf16* __restrict__ Al,
                                              const bf16* __restrict__ Bh, const bf16* __restrict__ Bl,
                                              const float* __restrict__ bias,
                                              bf16* __restrict__ Yh, bf16* __restrict__ Yl,
                                              float* __restrict__ OutF, float scale) {
  __shared__ bf16 sAh[4096], sBh[4096], sAl[4096], sBl[4096];
  int tid = threadIdx.x;
  int o0 = blockIdx.x * 128, t0 = blockIdx.y * 128;
  int wid = tid >> 6, lane = tid & 63;
  int wm = wid >> 1, wn = wid & 1, g = lane >> 4, r15 = lane & 15;
  f32x4 acc[4][4] = {};
  for (int kc = 0; kc < 1024; kc += 32) {
    __syncthreads();
    stage_tile(sAh, Ah, o0, kc, tid);
    stage_tile(sBh, Bh, t0, kc, tid);
    if (MODE == 0) {
      stage_tile(sAl, Al, o0, kc, tid);
      stage_tile(sBl, Bl, t0, kc, tid);
    }
    __syncthreads();
    bf16x8 ah[4], bh[4], al[4], bl[4];
#pragma unroll
    for (int f = 0; f < 4; ++f) {
      ah[f] = frag_ld(sAh, wm * 64 + f * 16 + r15, g);
      bh[f] = frag_ld(sBh, wn * 64 + f * 16 + r15, g);
      if (MODE == 0) {
        al[f] = frag_ld(sAl, wm * 64 + f * 16 + r15, g);
        bl[f] = frag_ld(sBl, wn * 64 + f * 16 + r15, g);
      }
    }
#pragma unroll
    for (int fm = 0; fm < 4; ++fm)
#pragma unroll
      for (int fn = 0; fn < 4; ++fn) {
        acc[fm][fn] = MFMA16(ah[fm], bh[fn], acc[fm][fn]);
        if (MODE == 0) {
          acc[fm][fn] = MFMA16(ah[fm], bl[fn], acc[fm][fn]);
          acc[fm][fn] = MFMA16(al[fm], bh[fn], acc[fm][fn]);
        }
      }
  }
#pragma unroll
  for (int fm = 0; fm < 4; ++fm)
#pragma unroll
    for (int fn = 0; fn < 4; ++fn) {
      int ob = o0 + wm * 64 + fm * 16 + 4 * g;  // D-frag rows = M(o), 4 consecutive
      int t  = t0 + wn * 64 + fn * 16 + r15;    // D-frag col  = N(t)
      if (MODE == 0) {
        int bb = t >> 11, tl = t & 2047, hh = ob >> 6, dd = ob & 63;
        size_t base = (((size_t)bb * 16 + hh) * 2048 + tl) * 64 + dd;
        bf16x4 vh, vl;
#pragma unroll
        for (int r = 0; r < 4; ++r) {
          float y = (acc[fm][fn][r] + bias[ob + r]) * scale;
          bf16 h = (bf16)y;
          vh[r] = h;
          vl[r] = (bf16)(y - (float)h);
        }
        *(bf16x4*)(Yh + base) = vh;
        *(bf16x4*)(Yl + base) = vl;
      } else {
        f32x4 v;
#pragma unroll
        for (int r = 0; r < 4; ++r) v[r] = acc[fm][fn][r] + bias[ob + r];
        *(f32x4*)(OutF + (size_t)t * 1024 + ob) = v;
      }
    }
}

// ---------------- normal-orientation GEMM for V:  Y[t][o] = sum_c X[t][c] W[o][c] + b[o]
// writes V transposed: VT[b][h][d][t] bf16 (so PV B-fragments are contiguous)
__global__ __launch_bounds__(256) void gemm_v(const bf16* __restrict__ X, const bf16* __restrict__ W,
                                              const float* __restrict__ bias, bf16* __restrict__ VT) {
  __shared__ bf16 sA[4096], sB[4096];
  int tid = threadIdx.x;
  int t0 = blockIdx.x * 128, o0 = blockIdx.y * 128;
  int wid = tid >> 6, lane = tid & 63;
  int wm = wid >> 1, wn = wid & 1, g = lane >> 4, r15 = lane & 15;
  f32x4 acc[4][4] = {};
  for (int kc = 0; kc < 1024; kc += 32) {
    __syncthreads();
    stage_tile(sA, X, t0, kc, tid);
    stage_tile(sB, W, o0, kc, tid);
    __syncthreads();
    bf16x8 af[4], bf_[4];
#pragma unroll
    for (int f = 0; f < 4; ++f) {
      af[f]  = frag_ld(sA, wm * 64 + f * 16 + r15, g);
      bf_[f] = frag_ld(sB, wn * 64 + f * 16 + r15, g);
    }
#pragma unroll
    for (int fm = 0; fm < 4; ++fm)
#pragma unroll
      for (int fn = 0; fn < 4; ++fn)
        acc[fm][fn] = MFMA16(af[fm], bf_[fn], acc[fm][fn]);
  }
#pragma unroll
  for (int fm = 0; fm < 4; ++fm)
#pragma unroll
    for (int fn = 0; fn < 4; ++fn) {
      int tb = t0 + wm * 64 + fm * 16 + 4 * g;  // rows = t, 4 consecutive
      int o  = o0 + wn * 64 + fn * 16 + r15;    // col = channel
      int bb = tb >> 11, tl = tb & 2047, hh = o >> 6, dd = o & 63;
      float bo = bias[o];
      bf16x4 v4;
#pragma unroll
      for (int r = 0; r < 4; ++r) v4[r] = (bf16)(acc[fm][fn][r] + bo);
      *(bf16x4*)(VT + (((size_t)bb * 16 + hh) * 64 + dd) * 2048 + tl) = v4;
    }
}

// ---------------- fused attention ----------------
// 1 block = (b, h, 16 q-rows). 512 threads (8 waves). probs row-block in LDS (bf16, stride 2052).
__global__ __launch_bounds__(512) void attn_kernel(
    const bf16* __restrict__ Qh, const bf16* __restrict__ Ql,
    const bf16* __restrict__ Kh, const bf16* __restrict__ Kl,
    const bf16* __restrict__ VT, const int* __restrict__ mask,
    float* __restrict__ wout, bf16* __restrict__ Abuf) {
  __shared__ bf16 probs[16 * 2052];   // 65,664 B
  __shared__ float part[4 * 16 * 16]; // PV partial (key-half 1)
  __shared__ float rz[16];
  int tid = threadIdx.x;
  int wid = tid >> 6, lane = tid & 63;
  int g = lane >> 4, r15 = lane & 15;
  int qt = blockIdx.x & 127, bh = blockIdx.x >> 7;
  int b = bh >> 4, h = bh & 15;
  int q0 = qt * 16;

  // Q fragments (A-operand: row = lane&15 = q, k = 8*(lane>>4)+j = d). Scale 1/8 folded into Qh/Ql.
  const bf16* qp  = Qh + ((size_t)bh * 2048 + q0 + r15) * 64 + 8 * g;
  const bf16* qlp = Ql + ((size_t)bh * 2048 + q0 + r15) * 64 + 8 * g;
  bf16x8 qh0 = *(const bf16x8*)(qp);
  bf16x8 qh1 = *(const bf16x8*)(qp + 32);
  bf16x8 ql0 = *(const bf16x8*)(qlp);
  bf16x8 ql1 = *(const bf16x8*)(qlp + 32);

  // phase 1: scores (split bf16 QK^T, 6 MFMAs / 16x16 tile) -> masked exp -> probs (bf16)
  const bf16* kbase  = Kh + (size_t)bh * 2048 * 64;
  const bf16* klbase = Kl + (size_t)bh * 2048 * 64;
#pragma unroll 2
  for (int i = 0; i < 16; ++i) {
    int k0 = (wid + 8 * i) * 16;
    const bf16* kp  = kbase  + (size_t)(k0 + r15) * 64 + 8 * g;
    const bf16* klp = klbase + (size_t)(k0 + r15) * 64 + 8 * g;
    bf16x8 kh0 = *(const bf16x8*)(kp);
    bf16x8 kh1 = *(const bf16x8*)(kp + 32);
    bf16x8 kl0 = *(const bf16x8*)(klp);
    bf16x8 kl1 = *(const bf16x8*)(klp + 32);
    f32x4 s = {0.f, 0.f, 0.f, 0.f};
    s = MFMA16(qh0, kh0, s);
    s = MFMA16(qh1, kh1, s);
    s = MFMA16(qh0, kl0, s);
    s = MFMA16(qh1, kl1, s);
    s = MFMA16(ql0, kh0, s);
    s = MFMA16(ql1, kh1, s);
    int mk = mask[b * 2048 + k0 + r15];
#pragma unroll
    for (int r = 0; r < 4; ++r) {
      float e = mk ? 0.0f : __expf(s[r]);  // exp without max-sub: scores ~N(0,1), safe
      probs[(4 * g + r) * 2052 + k0 + r15] = (bf16)e;
    }
  }
  __syncthreads();

  // phase 2: row sums -> rz (wheel: z==0 -> 0)
  {
    int row = tid >> 5, c = tid & 31;
    float z = 0.f;
#pragma unroll
    for (int i = 0; i < 8; ++i) {
      const bf16* p = &probs[row * 2052 + (c + 32 * i) * 8];
      bf16x4 a = *(const bf16x4*)p;
      bf16x4 d = *(const bf16x4*)(p + 4);
      z += (float)a[0] + (float)a[1] + (float)a[2] + (float)a[3] +
           (float)d[0] + (float)d[1] + (float)d[2] + (float)d[3];
    }
#pragma unroll
    for (int m = 1; m <= 16; m <<= 1) z += __shfl_xor(z, m);
    if (c == 0) rz[row] = (z > 0.f) ? 1.0f / z : 0.0f;
  }
  __syncthreads();

  // phase 3: normalized weights -> global (the 537 MB write, coalesced 32B/thread)
  {
    size_t wrow = (size_t)bh * 2048 + q0;
#pragma unroll
    for (int i = 0; i < 8; ++i) {
      int flat = i * 512 + tid;
      int row = flat >> 8;
      int col8 = (flat & 255) * 8;
      const bf16* p = &probs[row * 2052 + col8];
      bf16x4 a = *(const bf16x4*)p;
      bf16x4 d = *(const bf16x4*)(p + 4);
      float rzv = rz[row];
      f32x4 w0, w1;
#pragma unroll
      for (int r = 0; r < 4; ++r) {
        w0[r] = (float)a[r] * rzv;
        w1[r] = (float)d[r] * rzv;
      }
      float* dst = wout + (wrow + row) * 2048 + col8;
      *(f32x4*)dst = w0;
      *(f32x4*)(dst + 4) = w1;
    }
  }

  // phase 4: PV. 8 waves = 4 d-tiles x 2 key-halves; combine via LDS; scale by rz; write A.
  {
    int dt = wid & 3, k2 = wid >> 2, d0 = dt * 16;
    f32x4 acc = {0.f, 0.f, 0.f, 0.f};
    const bf16* vb = VT + ((size_t)bh * 64 + d0 + r15) * 2048 + k2 * 1024 + 8 * g;
    const bf16* pb = &probs[r15 * 2052 + k2 * 1024 + 8 * g];
#pragma unroll 4
    for (int s4 = 0; s4 < 32; ++s4) {
      bf16x4 p0 = *(const bf16x4*)(pb + 32 * s4);
      bf16x4 p1 = *(const bf16x4*)(pb + 32 * s4 + 4);
      bf16x8 pa = __builtin_shufflevector(p0, p1, 0, 1, 2, 3, 4, 5, 6, 7);
      bf16x8 vv = *(const bf16x8*)(vb + 32 * s4);
      acc = MFMA16(pa, vv, acc);
    }
    if (k2) {
#pragma unroll
      for (int r = 0; r < 4; ++r) part[(dt * 16 + 4 * g + r) * 16 + r15] = acc[r];
    }
    __syncthreads();
    if (!k2) {
#pragma unroll
      for (int r = 0; r < 4; ++r) {
        int q = 4 * g + r;
        float v = (acc[r] + part[(dt * 16 + q) * 16 + r15]) * rz[q];
        Abuf[((size_t)b * 2048 + q0 + q) * 1024 + h * 64 + d0 + r15] = (bf16)v;
      }
    }
  }
}

extern "C" void kernel_launch(void* const* d_in, const int* in_sizes, int n_in,
                              void* d_out, int out_size, void* d_ws, size_t ws_size,
                              hipStream_t stream) {
  const float* query = (const float*)d_in[0];
  const float* key_i = (const float*)d_in[1];
  const float* value = (const float*)d_in[2];
  const float* q_w = (const float*)d_in[3];
  const float* q_b = (const float*)d_in[4];
  const float* k_w = (const float*)d_in[5];
  const float* k_b = (const float*)d_in[6];
  const float* v_w = (const float*)d_in[7];
  const float* v_b = (const float*)d_in[8];
  const float* o_w = (const float*)d_in[9];
  const float* o_b = (const float*)d_in[10];
  const int* mask = (const int*)d_in[11];  // bool -> int32 per harness convention
  float* out = (float*)d_out;
  float* wout = out + 4194304;  // weights output region

  const size_t XB = 4096ull * 1024 * 2;  // 8,388,608 B (one [4096,1024] bf16 buffer)
  const size_t WB = 1024ull * 1024 * 2;  // 2,097,152 B
  if (ws_size < 7 * XB + 2 * WB) return;  // need ~63 MB scratch

  char* ws = (char*)d_ws;
  bf16* xh = (bf16*)ws;            ws += XB;  // also reused as Abuf after projections
  bf16* xl = (bf16*)ws;            ws += XB;
  bf16* wh = (bf16*)ws;            ws += WB;
  bf16* wl = (bf16*)ws;            ws += WB;
  bf16* Qh = (bf16*)ws;            ws += XB;
  bf16* Ql = (bf16*)ws;            ws += XB;
  bf16* Kh = (bf16*)ws;            ws += XB;
  bf16* Kl = (bf16*)ws;            ws += XB;
  bf16* VT = (bf16*)ws;            ws += XB;
  bf16* Abuf = xh;

  dim3 gT(8, 32), gV(32, 8);

  // Q = (query @ q_w^T + q_b) / 8, split hi/lo, [B,H,T,D]
  conv_split<<<4096, 256, 0, stream>>>(query, xh, xl, 4194304);
  conv_split<<<1024, 256, 0, stream>>>(q_w, wh, wl, 1048576);
  gemm_t<0><<<gT, 256, 0, stream>>>(wh, wl, xh, xl, q_b, Qh, Ql, nullptr, 0.125f);
  // K
  conv_split<<<4096, 256, 0, stream>>>(key_i, xh, xl, 4194304);
  conv_split<<<1024, 256, 0, stream>>>(k_w, wh, wl, 1048576);
  gemm_t<0><<<gT, 256, 0, stream>>>(wh, wl, xh, xl, k_b, Kh, Kl, nullptr, 1.0f);
  // V -> VT [B,H,D,T]
  conv_split<<<4096, 256, 0, stream>>>(value, xh, xl, 4194304);
  conv_split<<<1024, 256, 0, stream>>>(v_w, wh, wl, 1048576);
  gemm_v<<<gV, 256, 0, stream>>>(xh, wh, v_b, VT);
  // attention: weights -> d_out, A -> Abuf
  attn_kernel<<<4096, 512, 0, stream>>>(Qh, Ql, Kh, Kl, VT, mask, wout, Abuf);
  // out = A @ o_w^T + o_b
  conv_split<<<1024, 256, 0, stream>>>(o_w, wh, wl, 1048576);
  gemm_t<2><<<gT, 256, 0, stream>>>(wh, wl, Abuf, xl, o_b, nullptr, nullptr, out, 1.0f);
}

// Round 2
// 498.350 us; speedup vs baseline: 1.2329x; 1.2329x over previous
//
#include <hip/hip_runtime.h>
#include <math.h>

// WheelMultiheadAttention on MI355X (gfx950)
// B=2 T=2048 C=1024 H=16 D=64. Outputs: out [2,2048,1024] f32 then weights [2,16,2048,2048] f32.

typedef __bf16 bf16;
typedef __bf16 bf16x4 __attribute__((ext_vector_type(4)));
typedef __bf16 bf16x8 __attribute__((ext_vector_type(8)));
typedef _Float16 f16;
typedef _Float16 f16x4 __attribute__((ext_vector_type(4)));
typedef _Float16 f16x8 __attribute__((ext_vector_type(8)));
typedef float  f32x4  __attribute__((ext_vector_type(4)));

#define MFMA16(a, b, c) __builtin_amdgcn_mfma_f32_16x16x32_bf16((a), (b), (c), 0, 0, 0)
#define MFMAH(a, b, c)  __builtin_amdgcn_mfma_f32_16x16x32_f16((a), (b), (c), 0, 0, 0)

__device__ __forceinline__ void gload16(void* lds, const void* g) {
  __builtin_amdgcn_global_load_lds((__attribute__((address_space(1))) void*)(g),
                                   (__attribute__((address_space(3))) void*)(lds),
                                   16, 0, 0);
}

// ---------------- f32 -> bf16 hi/lo split ----------------
__global__ __launch_bounds__(256) void conv_split(const float* __restrict__ x,
                                                  bf16* __restrict__ hi,
                                                  bf16* __restrict__ lo, int n) {
  int i = (blockIdx.x * 256 + threadIdx.x) * 4;
  if (i >= n) return;
  f32x4 v = *(const f32x4*)(x + i);
  bf16x4 h4, l4;
#pragma unroll
  for (int r = 0; r < 4; ++r) {
    float f = v[r];
    bf16 h = (bf16)f;
    h4[r] = h;
    l4[r] = (bf16)(f - (float)h);
  }
  *(bf16x4*)(hi + i) = h4;
  *(bf16x4*)(lo + i) = l4;
}

// ---------------- shared GEMM helpers (128x128 tile, K-step 32, stride-1024 sources) ----
__device__ __forceinline__ void stage_tile(bf16* lds, const bf16* g, int row0, int kc, int tid) {
#pragma unroll
  for (int j = 0; j < 2; ++j) {
    int chunk = j * 256 + tid;
    int r = chunk >> 2, cpos = chunk & 3;
    int csrc = cpos ^ ((r >> 1) & 3);
    gload16((char*)lds + chunk * 16,
            (const char*)(g + (size_t)(row0 + r) * 1024 + kc) + csrc * 16);
  }
}

__device__ __forceinline__ bf16x8 frag_ld(const bf16* lds, int row, int g) {
  int pos = g ^ ((row >> 1) & 3);
  return *(const bf16x8*)((const char*)lds + row * 64 + pos * 16);
}

// ---------------- transposed-orientation GEMM:  Y[o][t] = sum_c W[o][c] * X[t][c] (+bias[o])
// MODE 0: split inputs (3 MFMAs), write (y*scale) as f16 to [B,H,T,D]
// MODE 2: plain, write f32 to Out[t][o] (final output projection)
template <int MODE>
__global__ __launch_bounds__(256) void gemm_t(const bf16* __restrict__ Ah, const bf16* __restrict__ Al,
                                              const bf16* __restrict__ Bh, const bf16* __restrict__ Bl,
                                              const float* __restrict__ bias,
                                              f16* __restrict__ Yf,
                                              float* __restrict__ OutF, float scale) {
  __shared__ bf16 sAh[4096], sBh[4096], sAl[4096], sBl[4096];
  int tid = threadIdx.x;
  int o0 = blockIdx.x * 128, t0 = blockIdx.y * 128;
  int wid = tid >> 6, lane = tid & 63;
  int wm = wid >> 1, wn = wid & 1, g = lane >> 4, r15 = lane & 15;
  f32x4 acc[4][4] = {};
  for (int kc = 0; kc < 1024; kc += 32) {
    __syncthreads();
    stage_tile(sAh, Ah, o0, kc, tid);
    stage_tile(sBh, Bh, t0, kc, tid);
    if (MODE == 0) {
      stage_tile(sAl, Al, o0, kc, tid);
      stage_tile(sBl, Bl, t0, kc, tid);
    }
    __syncthreads();
    bf16x8 ah[4], bh[4], al[4], bl[4];
#pragma unroll
    for (int f = 0; f < 4; ++f) {
      ah[f] = frag_ld(sAh, wm * 64 + f * 16 + r15, g);
      bh[f] = frag_ld(sBh, wn * 64 + f * 16 + r15, g);
      if (MODE == 0) {
        al[f] = frag_ld(sAl, wm * 64 + f * 16 + r15, g);
        bl[f] = frag_ld(sBl, wn * 64 + f * 16 + r15, g);
      }
    }
#pragma unroll
    for (int fm = 0; fm < 4; ++fm)
#pragma unroll
      for (int fn = 0; fn < 4; ++fn) {
        acc[fm][fn] = MFMA16(ah[fm], bh[fn], acc[fm][fn]);
        if (MODE == 0) {
          acc[fm][fn] = MFMA16(ah[fm], bl[fn], acc[fm][fn]);
          acc[fm][fn] = MFMA16(al[fm], bh[fn], acc[fm][fn]);
        }
      }
  }
#pragma unroll
  for (int fm = 0; fm < 4; ++fm)
#pragma unroll
    for (int fn = 0; fn < 4; ++fn) {
      int ob = o0 + wm * 64 + fm * 16 + 4 * g;  // D-frag rows = M(o), 4 consecutive
      int t  = t0 + wn * 64 + fn * 16 + r15;    // D-frag col  = N(t)
      if (MODE == 0) {
        int bb = t >> 11, tl = t & 2047, hh = ob >> 6, dd = ob & 63;
        size_t base = (((size_t)bb * 16 + hh) * 2048 + tl) * 64 + dd;
        f16x4 vh;
#pragma unroll
        for (int r = 0; r < 4; ++r)
          vh[r] = (f16)((acc[fm][fn][r] + bias[ob + r]) * scale);
        *(f16x4*)(Yf + base) = vh;
      } else {
        f32x4 v;
#pragma unroll
        for (int r = 0; r < 4; ++r) v[r] = acc[fm][fn][r] + bias[ob + r];
        *(f32x4*)(OutF + (size_t)t * 1024 + ob) = v;
      }
    }
}

// ---------------- normal-orientation GEMM for V:  Y[t][o] = sum_c X[t][c] W[o][c] + b[o]
// writes V transposed: VT[b][h][d][t] f16
__global__ __launch_bounds__(256) void gemm_v(const bf16* __restrict__ X, const bf16* __restrict__ W,
                                              const float* __restrict__ bias, f16* __restrict__ VT) {
  __shared__ bf16 sA[4096], sB[4096];
  int tid = threadIdx.x;
  int t0 = blockIdx.x * 128, o0 = blockIdx.y * 128;
  int wid = tid >> 6, lane = tid & 63;
  int wm = wid >> 1, wn = wid & 1, g = lane >> 4, r15 = lane & 15;
  f32x4 acc[4][4] = {};
  for (int kc = 0; kc < 1024; kc += 32) {
    __syncthreads();
    stage_tile(sA, X, t0, kc, tid);
    stage_tile(sB, W, o0, kc, tid);
    __syncthreads();
    bf16x8 af[4], bf_[4];
#pragma unroll
    for (int f = 0; f < 4; ++f) {
      af[f]  = frag_ld(sA, wm * 64 + f * 16 + r15, g);
      bf_[f] = frag_ld(sB, wn * 64 + f * 16 + r15, g);
    }
#pragma unroll
    for (int fm = 0; fm < 4; ++fm)
#pragma unroll
      for (int fn = 0; fn < 4; ++fn)
        acc[fm][fn] = MFMA16(af[fm], bf_[fn], acc[fm][fn]);
  }
#pragma unroll
  for (int fm = 0; fm < 4; ++fm)
#pragma unroll
    for (int fn = 0; fn < 4; ++fn) {
      int tb = t0 + wm * 64 + fm * 16 + 4 * g;  // rows = t, 4 consecutive
      int o  = o0 + wn * 64 + fn * 16 + r15;    // col = channel
      int bb = tb >> 11, tl = tb & 2047, hh = o >> 6, dd = o & 63;
      float bo = bias[o];
      f16x4 v4;
#pragma unroll
      for (int r = 0; r < 4; ++r) v4[r] = (f16)(acc[fm][fn][r] + bo);
      *(f16x4*)(VT + (((size_t)bb * 16 + hh) * 64 + dd) * 2048 + tl) = v4;
    }
}

// ---------------- fused attention (v3: f16, reg rowsum, prefetched, swizzled probs) ----
// 1 block = (b, h, 16 q-rows). 512 threads (8 waves).
// probs LDS layout: row-major [16][2048] f16, 16B granules XOR-swizzled by (row&7).
__global__ __launch_bounds__(512, 4) void attn_kernel(
    const f16* __restrict__ Qf, const f16* __restrict__ Kf,
    const f16* __restrict__ VT, const int* __restrict__ mask,
    float* __restrict__ wout, bf16* __restrict__ Abuf) {
  __shared__ f16 probs[16 * 2048];   // 64 KB
  __shared__ float aux[1024];        // PV partials (phase 4)
  __shared__ float ps[128];          // row-sum partials [row][wid]
  __shared__ float rz[16];
  int tid = threadIdx.x;
  int wid = tid >> 6, lane = tid & 63;
  int g = lane >> 4, r15 = lane & 15;
  int qt = blockIdx.x & 127, bh = blockIdx.x >> 7;
  int b = bh >> 4, h = bh & 15;
  int q0 = qt * 16;

  // mask bits for this thread's 16 k-positions (batched independent loads)
  unsigned mbits = 0;
#pragma unroll
  for (int i = 0; i < 16; ++i)
    mbits |= (mask[b * 2048 + (wid + 8 * i) * 16 + r15] ? 1u : 0u) << i;

  // Q fragments (A-operand: row=lane&15=q, k-chunk=lane>>4). Scale 1/8 folded into Qf.
  const f16* qp = Qf + ((size_t)bh * 2048 + q0 + r15) * 64 + 8 * g;
  f16x8 qh0 = *(const f16x8*)(qp);
  f16x8 qh1 = *(const f16x8*)(qp + 32);

  // phase 1: QK^T -> masked exp -> probs(f16, swizzled) ; row-sum partials in regs
  const f16* kb = Kf + (size_t)bh * 2048 * 64;
  float psum[4] = {0.f, 0.f, 0.f, 0.f};
  const f16* kp0 = kb + (size_t)(wid * 16 + r15) * 64 + 8 * g;
  f16x8 c0 = *(const f16x8*)(kp0);
  f16x8 c1 = *(const f16x8*)(kp0 + 32);
#pragma unroll
  for (int i = 0; i < 16; ++i) {
    f16x8 n0, n1;
    if (i < 15) {
      const f16* kp = kb + (size_t)((wid + 8 * (i + 1)) * 16 + r15) * 64 + 8 * g;
      n0 = *(const f16x8*)(kp);
      n1 = *(const f16x8*)(kp + 32);
    }
    f32x4 s = {0.f, 0.f, 0.f, 0.f};
    s = MFMAH(qh0, c0, s);
    s = MFMAH(qh1, c1, s);
    int k0 = (wid + 8 * i) * 16;
    float keep = ((mbits >> i) & 1) ? 0.0f : 1.0f;
    int col = k0 + r15;
    int gr = col >> 3, cl = col & 7;
#pragma unroll
    for (int r = 0; r < 4; ++r) {
      float e = keep * __expf(s[r]);
      psum[r] += e;
      int row = 4 * g + r;
      probs[row * 2048 + ((gr ^ (row & 7)) << 3) + cl] = (f16)e;
    }
    c0 = n0;
    c1 = n1;
  }

  // phase 2: row sums. in-wave over r15, then cross-wave via tiny LDS.
#pragma unroll
  for (int m = 1; m <= 8; m <<= 1) {
#pragma unroll
    for (int r = 0; r < 4; ++r) psum[r] += __shfl_xor(psum[r], m);
  }
  if (r15 == 0) {
#pragma unroll
    for (int r = 0; r < 4; ++r) ps[(4 * g + r) * 8 + wid] = psum[r];
  }
  __syncthreads();
  if (tid < 128) {
    float z = ps[tid];
#pragma unroll
    for (int m = 1; m <= 4; m <<= 1) z += __shfl_xor(z, m);
    if ((tid & 7) == 0) rz[tid >> 3] = (z > 0.f) ? 1.0f / z : 0.0f;
  }
  __syncthreads();

  // phase 3: normalized weights -> global (537 MB total, coalesced 32B/thread)
  {
    size_t wrow = (size_t)bh * 2048 + q0;
#pragma unroll
    for (int it = 0; it < 8; ++it) {
      int flat = it * 512 + tid;
      int row = flat >> 8;
      int gr0 = flat & 255;
      f16x8 p = *(const f16x8*)&probs[row * 2048 + ((gr0 ^ (row & 7)) << 3)];
      float rzv = rz[row];
      f32x4 w0, w1;
#pragma unroll
      for (int r = 0; r < 4; ++r) {
        w0[r] = (float)p[r] * rzv;
        w1[r] = (float)p[r + 4] * rzv;
      }
      float* dst = wout + (wrow + row) * 2048 + gr0 * 8;
      *(f32x4*)dst = w0;
      *(f32x4*)(dst + 4) = w1;
    }
  }

  // phase 4: PV. 8 waves = 4 d-tiles x 2 key-halves; combine via LDS; scale by rz.
  {
    int dt = wid & 3, k2 = wid >> 2, d0 = dt * 16;
    f32x4 acc = {0.f, 0.f, 0.f, 0.f};
    const f16* vb = VT + ((size_t)bh * 64 + d0 + r15) * 2048 + k2 * 1024 + 8 * g;
    int gbase = k2 * 128 + g, key = r15 & 7;
    const f16* prow = &probs[r15 * 2048];
    f16x8 vv = *(const f16x8*)(vb);
#pragma unroll
    for (int s4 = 0; s4 < 32; ++s4) {
      f16x8 nv;
      if (s4 < 31) nv = *(const f16x8*)(vb + 32 * (s4 + 1));
      f16x8 pa = *(const f16x8*)(prow + (((gbase + 4 * s4) ^ key) << 3));
      acc = MFMAH(pa, vv, acc);
      vv = nv;
    }
    if (k2) {
#pragma unroll
      for (int r = 0; r < 4; ++r) aux[(dt * 16 + 4 * g + r) * 16 + r15] = acc[r];
    }
    __syncthreads();
    if (!k2) {
#pragma unroll
      for (int r = 0; r < 4; ++r) {
        int q = 4 * g + r;
        float v = (acc[r] + aux[(dt * 16 + q) * 16 + r15]) * rz[q];
        Abuf[((size_t)b * 2048 + q0 + q) * 1024 + h * 64 + d0 + r15] = (bf16)v;
      }
    }
  }
}

extern "C" void kernel_launch(void* const* d_in, const int* in_sizes, int n_in,
                              void* d_out, int out_size, void* d_ws, size_t ws_size,
                              hipStream_t stream) {
  const float* query = (const float*)d_in[0];
  const float* key_i = (const float*)d_in[1];
  const float* value = (const float*)d_in[2];
  const float* q_w = (const float*)d_in[3];
  const float* q_b = (const float*)d_in[4];
  const float* k_w = (const float*)d_in[5];
  const float* k_b = (const float*)d_in[6];
  const float* v_w = (const float*)d_in[7];
  const float* v_b = (const float*)d_in[8];
  const float* o_w = (const float*)d_in[9];
  const float* o_b = (const float*)d_in[10];
  const int* mask = (const int*)d_in[11];
  float* out = (float*)d_out;
  float* wout = out + 4194304;  // weights output region

  const size_t XB = 4096ull * 1024 * 2;  // 8 MB (bf16 [4096,1024] or f16 same)
  const size_t WB = 1024ull * 1024 * 2;  // 2 MB
  if (ws_size < 5 * XB + 2 * WB) return;

  char* ws = (char*)d_ws;
  bf16* xh = (bf16*)ws;  ws += XB;   // reused as Abuf after projections
  bf16* xl = (bf16*)ws;  ws += XB;
  bf16* wh = (bf16*)ws;  ws += WB;
  bf16* wl = (bf16*)ws;  ws += WB;
  f16* Qf = (f16*)ws;    ws += XB;
  f16* Kf = (f16*)ws;    ws += XB;
  f16* VT = (f16*)ws;    ws += XB;
  bf16* Abuf = xh;

  dim3 gT(8, 32), gV(32, 8);

  // Q = (query @ q_w^T + q_b) / 8 -> f16 [B,H,T,D]
  conv_split<<<4096, 256, 0, stream>>>(query, xh, xl, 4194304);
  conv_split<<<1024, 256, 0, stream>>>(q_w, wh, wl, 1048576);
  gemm_t<0><<<gT, 256, 0, stream>>>(wh, wl, xh, xl, q_b, Qf, nullptr, 0.125f);
  // K -> f16 [B,H,T,D]
  conv_split<<<4096, 256, 0, stream>>>(key_i, xh, xl, 4194304);
  conv_split<<<1024, 256, 0, stream>>>(k_w, wh, wl, 1048576);
  gemm_t<0><<<gT, 256, 0, stream>>>(wh, wl, xh, xl, k_b, Kf, nullptr, 1.0f);
  // V -> VT [B,H,D,T] f16
  conv_split<<<4096, 256, 0, stream>>>(value, xh, xl, 4194304);
  conv_split<<<1024, 256, 0, stream>>>(v_w, wh, wl, 1048576);
  gemm_v<<<gV, 256, 0, stream>>>(xh, wh, v_b, VT);
  // attention: weights -> d_out, A -> Abuf
  attn_kernel<<<4096, 512, 0, stream>>>(Qf, Kf, VT, mask, wout, Abuf);
  // out = A @ o_w^T + o_b
  conv_split<<<1024, 256, 0, stream>>>(o_w, wh, wl, 1048576);
  gemm_t<2><<<gT, 256, 0, stream>>>(wh, wl, Abuf, xl, o_b, nullptr, out, 1.0f);
}

// Round 3
// 489.069 us; speedup vs baseline: 1.2563x; 1.0190x over previous
//
#include <hip/hip_runtime.h>
#include <math.h>

// WheelMultiheadAttention on MI355X (gfx950)
// B=2 T=2048 C=1024 H=16 D=64. Outputs: out [2,2048,1024] f32 then weights [2,16,2048,2048] f32.

typedef __bf16 bf16;
typedef __bf16 bf16x2 __attribute__((ext_vector_type(2)));
typedef __bf16 bf16x4 __attribute__((ext_vector_type(4)));
typedef __bf16 bf16x8 __attribute__((ext_vector_type(8)));
typedef _Float16 f16;
typedef _Float16 f16x4 __attribute__((ext_vector_type(4)));
typedef _Float16 f16x8 __attribute__((ext_vector_type(8)));
typedef float  f32x2  __attribute__((ext_vector_type(2)));
typedef float  f32x4  __attribute__((ext_vector_type(4)));

#define MFMA16(a, b, c) __builtin_amdgcn_mfma_f32_16x16x32_bf16((a), (b), (c), 0, 0, 0)
#define MFMAH(a, b, c)  __builtin_amdgcn_mfma_f32_16x16x32_f16((a), (b), (c), 0, 0, 0)

__device__ __forceinline__ void gload16(void* lds, const void* g) {
  __builtin_amdgcn_global_load_lds((__attribute__((address_space(1))) void*)(g),
                                   (__attribute__((address_space(3))) void*)(lds),
                                   16, 0, 0);
}

// ---------------- f32 -> bf16 hi/lo split ----------------
__global__ __launch_bounds__(256) void conv_split(const float* __restrict__ x,
                                                  bf16* __restrict__ hi,
                                                  bf16* __restrict__ lo, int n) {
  int i = (blockIdx.x * 256 + threadIdx.x) * 4;
  if (i >= n) return;
  f32x4 v = *(const f32x4*)(x + i);
  bf16x4 h4, l4;
#pragma unroll
  for (int r = 0; r < 4; ++r) {
    float f = v[r];
    bf16 h = (bf16)f;
    h4[r] = h;
    l4[r] = (bf16)(f - (float)h);
  }
  *(bf16x4*)(hi + i) = h4;
  *(bf16x4*)(lo + i) = l4;
}

// ---------------- shared GEMM helpers (128x128 tile, K-step 32, stride-1024 sources) ----
__device__ __forceinline__ void stage_tile(bf16* lds, const bf16* g, int row0, int kc, int tid) {
#pragma unroll
  for (int j = 0; j < 2; ++j) {
    int chunk = j * 256 + tid;
    int r = chunk >> 2, cpos = chunk & 3;
    int csrc = cpos ^ ((r >> 1) & 3);
    gload16((char*)lds + chunk * 16,
            (const char*)(g + (size_t)(row0 + r) * 1024 + kc) + csrc * 16);
  }
}

__device__ __forceinline__ bf16x8 frag_ld(const bf16* lds, int row, int g) {
  int pos = g ^ ((row >> 1) & 3);
  return *(const bf16x8*)((const char*)lds + row * 64 + pos * 16);
}

// ---------------- transposed-orientation GEMM:  Y[o][t] = sum_c W[o][c] * X[t][c] (+bias[o])
// MODE 0: split inputs (3 MFMAs), write (y*scale) as f16 to [B,H,T,D]
// MODE 2: plain, write f32 to Out[t][o] (final output projection)
template <int MODE>
__global__ __launch_bounds__(256) void gemm_t(const bf16* __restrict__ Ah, const bf16* __restrict__ Al,
                                              const bf16* __restrict__ Bh, const bf16* __restrict__ Bl,
                                              const float* __restrict__ bias,
                                              f16* __restrict__ Yf,
                                              float* __restrict__ OutF, float scale) {
  __shared__ bf16 sAh[4096], sBh[4096], sAl[4096], sBl[4096];
  int tid = threadIdx.x;
  int o0 = blockIdx.x * 128, t0 = blockIdx.y * 128;
  int wid = tid >> 6, lane = tid & 63;
  int wm = wid >> 1, wn = wid & 1, g = lane >> 4, r15 = lane & 15;
  f32x4 acc[4][4] = {};
  for (int kc = 0; kc < 1024; kc += 32) {
    __syncthreads();
    stage_tile(sAh, Ah, o0, kc, tid);
    stage_tile(sBh, Bh, t0, kc, tid);
    if (MODE == 0) {
      stage_tile(sAl, Al, o0, kc, tid);
      stage_tile(sBl, Bl, t0, kc, tid);
    }
    __syncthreads();
    bf16x8 ah[4], bh[4], al[4], bl[4];
#pragma unroll
    for (int f = 0; f < 4; ++f) {
      ah[f] = frag_ld(sAh, wm * 64 + f * 16 + r15, g);
      bh[f] = frag_ld(sBh, wn * 64 + f * 16 + r15, g);
      if (MODE == 0) {
        al[f] = frag_ld(sAl, wm * 64 + f * 16 + r15, g);
        bl[f] = frag_ld(sBl, wn * 64 + f * 16 + r15, g);
      }
    }
#pragma unroll
    for (int fm = 0; fm < 4; ++fm)
#pragma unroll
      for (int fn = 0; fn < 4; ++fn) {
        acc[fm][fn] = MFMA16(ah[fm], bh[fn], acc[fm][fn]);
        if (MODE == 0) {
          acc[fm][fn] = MFMA16(ah[fm], bl[fn], acc[fm][fn]);
          acc[fm][fn] = MFMA16(al[fm], bh[fn], acc[fm][fn]);
        }
      }
  }
#pragma unroll
  for (int fm = 0; fm < 4; ++fm)
#pragma unroll
    for (int fn = 0; fn < 4; ++fn) {
      int ob = o0 + wm * 64 + fm * 16 + 4 * g;  // D-frag rows = M(o), 4 consecutive
      int t  = t0 + wn * 64 + fn * 16 + r15;    // D-frag col  = N(t)
      if (MODE == 0) {
        int bb = t >> 11, tl = t & 2047, hh = ob >> 6, dd = ob & 63;
        size_t base = (((size_t)bb * 16 + hh) * 2048 + tl) * 64 + dd;
        f16x4 vh;
#pragma unroll
        for (int r = 0; r < 4; ++r)
          vh[r] = (f16)((acc[fm][fn][r] + bias[ob + r]) * scale);
        *(f16x4*)(Yf + base) = vh;
      } else {
        f32x4 v;
#pragma unroll
        for (int r = 0; r < 4; ++r) v[r] = acc[fm][fn][r] + bias[ob + r];
        *(f32x4*)(OutF + (size_t)t * 1024 + ob) = v;
      }
    }
}

// ---------------- normal-orientation GEMM for V:  Y[t][o] = sum_c X[t][c] W[o][c] + b[o]
// writes V in PV-slot-permuted layout: VT2[bh][t/32][d][slot], slot(g,j):
//   j<4 -> k32 = 4g+j ; j>=4 -> k32 = 16+4g+(j-4)   (matches attn PV A-frag register layout)
__global__ __launch_bounds__(256) void gemm_v(const bf16* __restrict__ X, const bf16* __restrict__ W,
                                              const float* __restrict__ bias, f16* __restrict__ VT2) {
  __shared__ bf16 sA[4096], sB[4096];
  int tid = threadIdx.x;
  int t0 = blockIdx.x * 128, o0 = blockIdx.y * 128;
  int wid = tid >> 6, lane = tid & 63;
  int wm = wid >> 1, wn = wid & 1, g = lane >> 4, r15 = lane & 15;
  f32x4 acc[4][4] = {};
  for (int kc = 0; kc < 1024; kc += 32) {
    __syncthreads();
    stage_tile(sA, X, t0, kc, tid);
    stage_tile(sB, W, o0, kc, tid);
    __syncthreads();
    bf16x8 af[4], bf_[4];
#pragma unroll
    for (int f = 0; f < 4; ++f) {
      af[f]  = frag_ld(sA, wm * 64 + f * 16 + r15, g);
      bf_[f] = frag_ld(sB, wn * 64 + f * 16 + r15, g);
    }
#pragma unroll
    for (int fm = 0; fm < 4; ++fm)
#pragma unroll
      for (int fn = 0; fn < 4; ++fn)
        acc[fm][fn] = MFMA16(af[fm], bf_[fn], acc[fm][fn]);
  }
#pragma unroll
  for (int fm = 0; fm < 4; ++fm)
#pragma unroll
    for (int fn = 0; fn < 4; ++fn) {
      int tb = t0 + wm * 64 + fm * 16 + 4 * g;  // rows = t, 4 consecutive
      int o  = o0 + wn * 64 + fn * 16 + r15;    // col = channel
      int bb = tb >> 11, tl = tb & 2047, hh = o >> 6, dd = o & 63;
      int ch = tl >> 5, c = tl & 31;
      int slotbase = (c < 16) ? ((c >> 2) << 3) : ((((c - 16) >> 2) << 3) + 4);
      float bo = bias[o];
      f16x4 v4;
#pragma unroll
      for (int r = 0; r < 4; ++r) v4[r] = (f16)(acc[fm][fn][r] + bo);
      *(f16x4*)(VT2 + ((((size_t)bb * 16 + hh) * 64 + ch) * 64 + dd) * 32 + slotbase) = v4;
    }
}

// ---------------- fused attention (v4: register-resident P, swapped QK^T) ----------------
// 1 block = (b, h, 16 q-rows), 512 threads (8 waves). Wave w owns k range [256w, 256w+256).
// Swapped QK^T: lane holds q = lane&15, k = 4*(lane>>4)+r per 16-k tile -> 16 f16x4 packed P.
// PV consumes P directly (slot-permuted VT2); LDS only for row-sum + PV cross-wave reduce.
__global__ __launch_bounds__(512, 4) void attn_kernel(
    const f16* __restrict__ Qf, const f16* __restrict__ Kf,
    const f16* __restrict__ VT2, const int* __restrict__ mask,
    float* __restrict__ wout, bf16* __restrict__ Abuf) {
  __shared__ float pvbuf[8 * 1088];  // [wave][q][68-padded d] partials, 34.8 KB
  __shared__ float ps[128];          // row-sum partials [q][wave]
  __shared__ float rz[16];
  int tid = threadIdx.x;
  int wid = tid >> 6, lane = tid & 63;
  int g = lane >> 4, r15 = lane & 15;
  int qt = blockIdx.x & 127, bh = blockIdx.x >> 7;
  int b = bh >> 4, h = bh & 15;
  int q0 = qt * 16;

  // Q fragments (B-operand now: col=lane&15=q, k-dim=8g+j). Scale 1/8 folded into Qf.
  const f16* qp = Qf + ((size_t)bh * 2048 + q0 + r15) * 64 + 8 * g;
  f16x8 qh0 = *(const f16x8*)(qp);
  f16x8 qh1 = *(const f16x8*)(qp + 32);

  // phase 1: swapped QK^T -> masked exp -> packed P in registers; row-sum in regs
  const f16* kp = Kf + ((size_t)bh * 2048 + wid * 256 + r15) * 64 + 8 * g;
  const int* mp = mask + b * 2048 + wid * 256 + 4 * g;
  f16x8 c0 = *(const f16x8*)(kp);
  f16x8 c1 = *(const f16x8*)(kp + 32);
  int4 cm = *(const int4*)(mp);
  float psum = 0.f;
  f16x4 p16[16];
#pragma unroll
  for (int s = 0; s < 16; ++s) {
    f16x8 n0, n1;
    int4 nm;
    if (s < 15) {
      n0 = *(const f16x8*)(kp + (s + 1) * 1024);
      n1 = *(const f16x8*)(kp + (s + 1) * 1024 + 32);
      nm = *(const int4*)(mp + (s + 1) * 16);
    }
    f32x4 sc = {0.f, 0.f, 0.f, 0.f};
    sc = MFMAH(c0, qh0, sc);   // A = K tile (rows = k), B = Q (cols = q)
    sc = MFMAH(c1, qh1, sc);
    int mr[4] = {cm.x, cm.y, cm.z, cm.w};
    f16x4 pk;
#pragma unroll
    for (int r = 0; r < 4; ++r) {
      float e = mr[r] ? 0.f : __expf(sc[r]);
      psum += e;
      pk[r] = (f16)e;
    }
    p16[s] = pk;
    c0 = n0;
    c1 = n1;
    cm = nm;
  }

  // in-wave row-sum reduce across g (lanes sharing q=r15)
  psum += __shfl_xor(psum, 16);
  psum += __shfl_xor(psum, 32);
  if (lane < 16) ps[lane * 8 + wid] = psum;

  // phase 2: PV over this wave's 256 k (A = packed P regs, B = slot-permuted VT2)
  f32x4 acc[4] = {};
  {
    const f16* vb = VT2 + (((size_t)bh * 64 + wid * 8) * 64 + r15) * 32 + g * 8;
#pragma unroll
    for (int t = 0; t < 8; ++t) {
      f16x8 af = __builtin_shufflevector(p16[2 * t], p16[2 * t + 1], 0, 1, 2, 3, 4, 5, 6, 7);
#pragma unroll
      for (int dt = 0; dt < 4; ++dt) {
        f16x8 bv = *(const f16x8*)(vb + t * 2048 + dt * 512);
        acc[dt] = MFMAH(af, bv, acc[dt]);  // D: col = d-local (r15), row = q (4g+r)
      }
    }
#pragma unroll
    for (int dt = 0; dt < 4; ++dt)
#pragma unroll
      for (int r = 0; r < 4; ++r)
        pvbuf[wid * 1088 + (4 * g + r) * 68 + dt * 16 + r15] = acc[dt][r];
  }
  __syncthreads();

  // finalize row sums -> rz
  if (tid < 128) {
    float z = ps[tid];
#pragma unroll
    for (int m = 1; m <= 4; m <<= 1) z += __shfl_xor(z, m);
    if ((tid & 7) == 0) rz[tid >> 3] = (z > 0.f) ? 1.0f / z : 0.0f;
  }
  __syncthreads();

  // phase 3: weights from registers -> global (537 MB total)
  {
    float rzv = rz[r15];
    float* wb = wout + ((size_t)bh * 2048 + q0 + r15) * 2048 + wid * 256 + 4 * g;
#pragma unroll
    for (int s = 0; s < 16; ++s) {
      f16x4 pk = p16[s];
      f32x4 wv;
#pragma unroll
      for (int r = 0; r < 4; ++r) wv[r] = (float)pk[r] * rzv;
      *(f32x4*)(wb + s * 16) = wv;
    }
  }

  // phase 4: cross-wave PV reduce -> Abuf (bf16 [B,T,C])
  {
    int q = tid >> 5, d = (tid & 31) * 2;
    float a0 = 0.f, a1 = 0.f;
#pragma unroll
    for (int w8 = 0; w8 < 8; ++w8) {
      f32x2 v = *(const f32x2*)&pvbuf[w8 * 1088 + q * 68 + d];
      a0 += v[0];
      a1 += v[1];
    }
    float rzq = rz[q];
    bf16x2 o2 = {(bf16)(a0 * rzq), (bf16)(a1 * rzq)};
    *(bf16x2*)(Abuf + ((size_t)b * 2048 + q0 + q) * 1024 + h * 64 + d) = o2;
  }
}

extern "C" void kernel_launch(void* const* d_in, const int* in_sizes, int n_in,
                              void* d_out, int out_size, void* d_ws, size_t ws_size,
                              hipStream_t stream) {
  const float* query = (const float*)d_in[0];
  const float* key_i = (const float*)d_in[1];
  const float* value = (const float*)d_in[2];
  const float* q_w = (const float*)d_in[3];
  const float* q_b = (const float*)d_in[4];
  const float* k_w = (const float*)d_in[5];
  const float* k_b = (const float*)d_in[6];
  const float* v_w = (const float*)d_in[7];
  const float* v_b = (const float*)d_in[8];
  const float* o_w = (const float*)d_in[9];
  const float* o_b = (const float*)d_in[10];
  const int* mask = (const int*)d_in[11];
  float* out = (float*)d_out;
  float* wout = out + 4194304;  // weights output region

  const size_t XB = 4096ull * 1024 * 2;  // 8 MB
  const size_t WB = 1024ull * 1024 * 2;  // 2 MB
  if (ws_size < 5 * XB + 2 * WB) return;

  char* ws = (char*)d_ws;
  bf16* xh = (bf16*)ws;  ws += XB;   // reused as Abuf after projections
  bf16* xl = (bf16*)ws;  ws += XB;
  bf16* wh = (bf16*)ws;  ws += WB;
  bf16* wl = (bf16*)ws;  ws += WB;
  f16* Qf = (f16*)ws;    ws += XB;
  f16* Kf = (f16*)ws;    ws += XB;
  f16* VT2 = (f16*)ws;   ws += XB;
  bf16* Abuf = xh;

  dim3 gT(8, 32), gV(32, 8);

  // Q = (query @ q_w^T + q_b) / 8 -> f16 [B,H,T,D]
  conv_split<<<4096, 256, 0, stream>>>(query, xh, xl, 4194304);
  conv_split<<<1024, 256, 0, stream>>>(q_w, wh, wl, 1048576);
  gemm_t<0><<<gT, 256, 0, stream>>>(wh, wl, xh, xl, q_b, Qf, nullptr, 0.125f);
  // K -> f16 [B,H,T,D]
  conv_split<<<4096, 256, 0, stream>>>(key_i, xh, xl, 4194304);
  conv_split<<<1024, 256, 0, stream>>>(k_w, wh, wl, 1048576);
  gemm_t<0><<<gT, 256, 0, stream>>>(wh, wl, xh, xl, k_b, Kf, nullptr, 1.0f);
  // V -> VT2 slot-permuted [B,H,T/32,D,32]
  conv_split<<<4096, 256, 0, stream>>>(value, xh, xl, 4194304);
  conv_split<<<1024, 256, 0, stream>>>(v_w, wh, wl, 1048576);
  gemm_v<<<gV, 256, 0, stream>>>(xh, wh, v_b, VT2);
  // attention: weights -> d_out, A -> Abuf
  attn_kernel<<<4096, 512, 0, stream>>>(Qf, Kf, VT2, mask, wout, Abuf);
  // out = A @ o_w^T + o_b
  conv_split<<<1024, 256, 0, stream>>>(o_w, wh, wl, 1048576);
  gemm_t<2><<<gT, 256, 0, stream>>>(wh, wl, Abuf, xl, o_b, nullptr, out, 1.0f);
}

// Round 4
// 369.583 us; speedup vs baseline: 1.6625x; 1.3233x over previous
//
#include <hip/hip_runtime.h>
#include <math.h>

// WheelMultiheadAttention on MI355X (gfx950) — v5: all-f16 pipeline, 2-chain attn, NT weight stores
// B=2 T=2048 C=1024 H=16 D=64. Outputs: out [2,2048,1024] f32 then weights [2,16,2048,2048] f32.

typedef _Float16 f16;
typedef _Float16 f16x2 __attribute__((ext_vector_type(2)));
typedef _Float16 f16x4 __attribute__((ext_vector_type(4)));
typedef _Float16 f16x8 __attribute__((ext_vector_type(8)));
typedef float  f32x2  __attribute__((ext_vector_type(2)));
typedef float  f32x4  __attribute__((ext_vector_type(4)));

#define MFMAH(a, b, c)  __builtin_amdgcn_mfma_f32_16x16x32_f16((a), (b), (c), 0, 0, 0)

__device__ __forceinline__ void gload16(void* lds, const void* g) {
  __builtin_amdgcn_global_load_lds((__attribute__((address_space(1))) void*)(g),
                                   (__attribute__((address_space(3))) void*)(lds),
                                   16, 0, 0);
}

// ---------------- fused f32 -> f16 convert (query|key|value|q_w|k_w|v_w|o_w into one buffer) ----
// element offsets inside xf: q:0 k:4194304 v:8388608 qw:12582912 kw:13631488 vw:14680064 ow:15728640
__global__ __launch_bounds__(256) void conv_f16(const float* __restrict__ q, const float* __restrict__ k,
                                                const float* __restrict__ v, const float* __restrict__ qw,
                                                const float* __restrict__ kw, const float* __restrict__ vw,
                                                const float* __restrict__ ow, f16* __restrict__ xf) {
  long long i = ((long long)blockIdx.x * 256 + threadIdx.x) * 4;
  const float* src;
  long long off;
  if (i < 4194304)       { src = q;  off = 0; }
  else if (i < 8388608)  { src = k;  off = 4194304; }
  else if (i < 12582912) { src = v;  off = 8388608; }
  else if (i < 13631488) { src = qw; off = 12582912; }
  else if (i < 14680064) { src = kw; off = 13631488; }
  else if (i < 15728640) { src = vw; off = 14680064; }
  else                   { src = ow; off = 15728640; }
  f32x4 val = *(const f32x4*)(src + (i - off));
  f16x4 h;
#pragma unroll
  for (int r = 0; r < 4; ++r) h[r] = (f16)val[r];
  *(f16x4*)(xf + i) = h;
}

// ---------------- shared GEMM helpers (128x128 tile, K-step 32, stride-1024 sources) ----
__device__ __forceinline__ void stage_tile(f16* lds, const f16* g, int row0, int kc, int tid) {
#pragma unroll
  for (int j = 0; j < 2; ++j) {
    int chunk = j * 256 + tid;
    int r = chunk >> 2, cpos = chunk & 3;
    int csrc = cpos ^ ((r >> 1) & 3);
    gload16((char*)lds + chunk * 16,
            (const char*)(g + (size_t)(row0 + r) * 1024 + kc) + csrc * 16);
  }
}

__device__ __forceinline__ f16x8 frag_ld(const f16* lds, int row, int g) {
  int pos = g ^ ((row >> 1) & 3);
  return *(const f16x8*)((const char*)lds + row * 64 + pos * 16);
}

// K-loop core: acc[fm][fn] += A[o0+..][:] . X[t0+..][:] over K=1024
__device__ __forceinline__ void gemm_core(const f16* A, const f16* X, int o0, int t0, int tid,
                                          f16* sA, f16* sB, f32x4 acc[4][4]) {
  int wid = tid >> 6, lane = tid & 63;
  int wm = wid >> 1, wn = wid & 1, g = lane >> 4, r15 = lane & 15;
  for (int kc = 0; kc < 1024; kc += 32) {
    __syncthreads();
    stage_tile(sA, A, o0, kc, tid);
    stage_tile(sB, X, t0, kc, tid);
    __syncthreads();
    f16x8 a[4], x[4];
#pragma unroll
    for (int f = 0; f < 4; ++f) {
      a[f] = frag_ld(sA, wm * 64 + f * 16 + r15, g);
      x[f] = frag_ld(sB, wn * 64 + f * 16 + r15, g);
    }
#pragma unroll
    for (int fm = 0; fm < 4; ++fm)
#pragma unroll
      for (int fn = 0; fn < 4; ++fn)
        acc[fm][fn] = MFMAH(a[fm], x[fn], acc[fm][fn]);
  }
}

// ---------------- Q/K projection (batched over blockIdx.z): Y[o][t] = W[o][:].X[t][:] + b
__global__ __launch_bounds__(256) void gemm_qk(const f16* __restrict__ xf,
                                               const float* __restrict__ q_b, const float* __restrict__ k_b,
                                               f16* __restrict__ Qf, f16* __restrict__ Kf) {
  __shared__ f16 sA[4096], sB[4096];
  int z = blockIdx.z;
  const f16* A = xf + (z ? 13631488 : 12582912);
  const f16* X = xf + (z ? 4194304 : 0);
  const float* bias = z ? k_b : q_b;
  f16* Yf = z ? Kf : Qf;
  float scale = z ? 1.0f : 0.125f;
  int tid = threadIdx.x;
  int o0 = blockIdx.x * 128, t0 = blockIdx.y * 128;
  int wid = tid >> 6, lane = tid & 63;
  int wm = wid >> 1, wn = wid & 1, g = lane >> 4, r15 = lane & 15;
  f32x4 acc[4][4] = {};
  gemm_core(A, X, o0, t0, tid, sA, sB, acc);
#pragma unroll
  for (int fm = 0; fm < 4; ++fm)
#pragma unroll
    for (int fn = 0; fn < 4; ++fn) {
      int ob = o0 + wm * 64 + fm * 16 + 4 * g;  // 4 consecutive o in regs
      int t  = t0 + wn * 64 + fn * 16 + r15;
      int bb = t >> 11, tl = t & 2047, hh = ob >> 6, dd = ob & 63;
      size_t base = (((size_t)bb * 16 + hh) * 2048 + tl) * 64 + dd;
      f16x4 vh;
#pragma unroll
      for (int r = 0; r < 4; ++r)
        vh[r] = (f16)((acc[fm][fn][r] + bias[ob + r]) * scale);
      *(f16x4*)(Yf + base) = vh;
    }
}

// ---------------- V projection: Y[t][o] = X[t][:].W[o][:] + b, slot-permuted VT2 ------
// VT2[bh][t/32][d][slot]; slot(g,j): j<4 -> k32=4g+j ; j>=4 -> k32=16+4g+(j-4)
__global__ __launch_bounds__(256) void gemm_v(const f16* __restrict__ xf,
                                              const float* __restrict__ bias, f16* __restrict__ VT2) {
  __shared__ f16 sA[4096], sB[4096];
  const f16* X = xf + 8388608;   // value
  const f16* W = xf + 14680064;  // v_w
  int tid = threadIdx.x;
  int t0 = blockIdx.x * 128, o0 = blockIdx.y * 128;
  int wid = tid >> 6, lane = tid & 63;
  int wm = wid >> 1, wn = wid & 1, g = lane >> 4, r15 = lane & 15;
  f32x4 acc[4][4] = {};
  gemm_core(X, W, t0, o0, tid, sA, sB, acc);
#pragma unroll
  for (int fm = 0; fm < 4; ++fm)
#pragma unroll
    for (int fn = 0; fn < 4; ++fn) {
      int tb = t0 + wm * 64 + fm * 16 + 4 * g;  // 4 consecutive t in regs
      int o  = o0 + wn * 64 + fn * 16 + r15;
      int bb = tb >> 11, tl = tb & 2047, hh = o >> 6, dd = o & 63;
      int ch = tl >> 5, c = tl & 31;
      int slotbase = (c < 16) ? ((c >> 2) << 3) : ((((c - 16) >> 2) << 3) + 4);
      float bo = bias[o];
      f16x4 v4;
#pragma unroll
      for (int r = 0; r < 4; ++r) v4[r] = (f16)(acc[fm][fn][r] + bo);
      *(f16x4*)(VT2 + ((((size_t)bb * 16 + hh) * 64 + ch) * 64 + dd) * 32 + slotbase) = v4;
    }
}

// ---------------- O projection: Out[t][o] = A[t][:].o_w[o][:] + b, f32 ----------------
__global__ __launch_bounds__(256) void gemm_o(const f16* __restrict__ xf, const f16* __restrict__ Abuf,
                                              const float* __restrict__ o_b, float* __restrict__ OutF) {
  __shared__ f16 sA[4096], sB[4096];
  const f16* A = xf + 15728640;  // o_w
  int tid = threadIdx.x;
  int o0 = blockIdx.x * 128, t0 = blockIdx.y * 128;
  int wid = tid >> 6, lane = tid & 63;
  int wm = wid >> 1, wn = wid & 1, g = lane >> 4, r15 = lane & 15;
  f32x4 acc[4][4] = {};
  gemm_core(A, Abuf, o0, t0, tid, sA, sB, acc);
#pragma unroll
  for (int fm = 0; fm < 4; ++fm)
#pragma unroll
    for (int fn = 0; fn < 4; ++fn) {
      int ob = o0 + wm * 64 + fm * 16 + 4 * g;
      int t  = t0 + wn * 64 + fn * 16 + r15;
      f32x4 v;
#pragma unroll
      for (int r = 0; r < 4; ++r) v[r] = acc[fm][fn][r] + o_b[ob + r];
      *(f32x4*)(OutF + (size_t)t * 1024 + ob) = v;
    }
}

// ---------------- fused attention (v5: register P, 2 independent k-chains, NT stores) --------
__global__ __launch_bounds__(512, 4) void attn_kernel(
    const f16* __restrict__ Qf, const f16* __restrict__ Kf,
    const f16* __restrict__ VT2, const int* __restrict__ mask,
    float* __restrict__ wout, f16* __restrict__ Abuf) {
  __shared__ float pvbuf[8 * 1088];  // [wave][q][68-padded d] partials
  __shared__ float ps[128];          // row-sum partials [q][wave]
  __shared__ float rz[16];
  int tid = threadIdx.x;
  int wid = tid >> 6, lane = tid & 63;
  int g = lane >> 4, r15 = lane & 15;
  int qt = blockIdx.x & 127, bh = blockIdx.x >> 7;
  int b = bh >> 4, h = bh & 15;
  int q0 = qt * 16;

  // Q fragments (B-operand: col = q = lane&15). 1/8 scale folded into Qf.
  const f16* qp = Qf + ((size_t)bh * 2048 + q0 + r15) * 64 + 8 * g;
  f16x8 qh0 = *(const f16x8*)(qp);
  f16x8 qh1 = *(const f16x8*)(qp + 32);

  // pack this lane's 64 mask bits (k = wid*256 + t*16 + 4g + r) into two 32-bit masks
  const int* mp = mask + b * 2048 + wid * 256 + 4 * g;
  unsigned mlo = 0, mhi = 0;
#pragma unroll
  for (int t = 0; t < 8; ++t) {
    int4 ma = *(const int4*)(mp + t * 16);
    int4 mb = *(const int4*)(mp + 128 + t * 16);
    mlo |= ((ma.x ? 1u : 0u) << (4 * t)) | ((ma.y ? 1u : 0u) << (4 * t + 1)) |
           ((ma.z ? 1u : 0u) << (4 * t + 2)) | ((ma.w ? 1u : 0u) << (4 * t + 3));
    mhi |= ((mb.x ? 1u : 0u) << (4 * t)) | ((mb.y ? 1u : 0u) << (4 * t + 1)) |
           ((mb.z ? 1u : 0u) << (4 * t + 2)) | ((mb.w ? 1u : 0u) << (4 * t + 3));
  }

  // phase 1: swapped QK^T, two independent chains -> masked exp -> packed P regs
  const f16* kpA = Kf + ((size_t)bh * 2048 + wid * 256 + r15) * 64 + 8 * g;
  const f16* kpB = kpA + 8 * 1024;
  f16x8 cA0 = *(const f16x8*)(kpA);
  f16x8 cA1 = *(const f16x8*)(kpA + 32);
  f16x8 cB0 = *(const f16x8*)(kpB);
  f16x8 cB1 = *(const f16x8*)(kpB + 32);
  float psum = 0.f;
  f16x4 p16[16];
#pragma unroll
  for (int s = 0; s < 8; ++s) {
    f16x8 nA0, nA1, nB0, nB1;
    if (s < 7) {
      nA0 = *(const f16x8*)(kpA + (s + 1) * 1024);
      nA1 = *(const f16x8*)(kpA + (s + 1) * 1024 + 32);
      nB0 = *(const f16x8*)(kpB + (s + 1) * 1024);
      nB1 = *(const f16x8*)(kpB + (s + 1) * 1024 + 32);
    }
    f32x4 sa = {0.f, 0.f, 0.f, 0.f}, sb = {0.f, 0.f, 0.f, 0.f};
    sa = MFMAH(cA0, qh0, sa);   // A = K-tile rows (k), B = Q (cols q)
    sb = MFMAH(cB0, qh0, sb);
    sa = MFMAH(cA1, qh1, sa);
    sb = MFMAH(cB1, qh1, sb);
    f16x4 pa, pb;
#pragma unroll
    for (int r = 0; r < 4; ++r) {
      float eA = ((mlo >> (4 * s + r)) & 1) ? 0.f : __expf(sa[r]);
      float eB = ((mhi >> (4 * s + r)) & 1) ? 0.f : __expf(sb[r]);
      psum += eA + eB;
      pa[r] = (f16)eA;
      pb[r] = (f16)eB;
    }
    p16[s] = pa;
    p16[s + 8] = pb;
    cA0 = nA0; cA1 = nA1; cB0 = nB0; cB1 = nB1;
  }

  // in-wave row-sum reduce across g (lanes sharing q=r15)
  psum += __shfl_xor(psum, 16);
  psum += __shfl_xor(psum, 32);
  if (lane < 16) ps[lane * 8 + wid] = psum;

  // phase 2: PV over this wave's 256 k (A = packed P regs, B = slot-permuted VT2)
  f32x4 acc[4] = {};
  {
    const f16* vb = VT2 + (((size_t)bh * 64 + wid * 8) * 64 + r15) * 32 + g * 8;
#pragma unroll
    for (int t = 0; t < 8; ++t) {
      f16x8 af = __builtin_shufflevector(p16[2 * t], p16[2 * t + 1], 0, 1, 2, 3, 4, 5, 6, 7);
#pragma unroll
      for (int dt = 0; dt < 4; ++dt) {
        f16x8 bv = *(const f16x8*)(vb + t * 2048 + dt * 512);
        acc[dt] = MFMAH(af, bv, acc[dt]);  // D: col = d-local (r15), row = q (4g+r)
      }
    }
#pragma unroll
    for (int dt = 0; dt < 4; ++dt)
#pragma unroll
      for (int r = 0; r < 4; ++r)
        pvbuf[wid * 1088 + (4 * g + r) * 68 + dt * 16 + r15] = acc[dt][r];
  }
  __syncthreads();

  // finalize row sums -> rz
  if (tid < 128) {
    float z = ps[tid];
#pragma unroll
    for (int m = 1; m <= 4; m <<= 1) z += __shfl_xor(z, m);
    if ((tid & 7) == 0) rz[tid >> 3] = (z > 0.f) ? 1.0f / z : 0.0f;
  }
  __syncthreads();

  // phase 3: weights from regs -> global, NON-TEMPORAL (537 MB total; keep K/V in L2)
  {
    float rzv = rz[r15];
    float* wb = wout + ((size_t)bh * 2048 + q0 + r15) * 2048 + wid * 256 + 4 * g;
#pragma unroll
    for (int s = 0; s < 16; ++s) {
      f16x4 pk = p16[s];
      f32x4 wv;
#pragma unroll
      for (int r = 0; r < 4; ++r) wv[r] = (float)pk[r] * rzv;
      __builtin_nontemporal_store(wv, (f32x4*)(wb + s * 16));
    }
  }

  // phase 4: cross-wave PV reduce -> Abuf (f16 [B,T,C])
  {
    int q = tid >> 5, d = (tid & 31) * 2;
    float a0 = 0.f, a1 = 0.f;
#pragma unroll
    for (int w8 = 0; w8 < 8; ++w8) {
      f32x2 v = *(const f32x2*)&pvbuf[w8 * 1088 + q * 68 + d];
      a0 += v[0];
      a1 += v[1];
    }
    float rzq = rz[q];
    f16x2 o2 = {(f16)(a0 * rzq), (f16)(a1 * rzq)};
    *(f16x2*)(Abuf + ((size_t)b * 2048 + q0 + q) * 1024 + h * 64 + d) = o2;
  }
}

extern "C" void kernel_launch(void* const* d_in, const int* in_sizes, int n_in,
                              void* d_out, int out_size, void* d_ws, size_t ws_size,
                              hipStream_t stream) {
  const float* query = (const float*)d_in[0];
  const float* key_i = (const float*)d_in[1];
  const float* value = (const float*)d_in[2];
  const float* q_w = (const float*)d_in[3];
  const float* q_b = (const float*)d_in[4];
  const float* k_w = (const float*)d_in[5];
  const float* k_b = (const float*)d_in[6];
  const float* v_w = (const float*)d_in[7];
  const float* v_b = (const float*)d_in[8];
  const float* o_w = (const float*)d_in[9];
  const float* o_b = (const float*)d_in[10];
  const int* mask = (const int*)d_in[11];
  float* out = (float*)d_out;
  float* wout = out + 4194304;  // weights output region

  // ws: xf f16[16777216] (33.6MB) | Qf f16[4194304] | Kf f16[4194304]  -> 50.4MB total
  const size_t XFB = 16777216ull * 2;
  const size_t QB = 4194304ull * 2;
  if (ws_size < XFB + 2 * QB) return;
  f16* xf = (f16*)d_ws;
  f16* Qf = (f16*)((char*)d_ws + XFB);
  f16* Kf = (f16*)((char*)d_ws + XFB + QB);
  f16* VT2 = xf;             // reuse query slot (dead after gemm_qk)
  f16* Abuf = xf + 4194304;  // reuse key slot (dead after gemm_qk)

  conv_f16<<<16384, 256, 0, stream>>>(query, key_i, value, q_w, k_w, v_w, o_w, xf);
  gemm_qk<<<dim3(8, 32, 2), 256, 0, stream>>>(xf, q_b, k_b, Qf, Kf);
  gemm_v<<<dim3(32, 8), 256, 0, stream>>>(xf, v_b, VT2);
  attn_kernel<<<4096, 512, 0, stream>>>(Qf, Kf, VT2, mask, wout, Abuf);
  gemm_o<<<dim3(8, 32), 256, 0, stream>>>(xf, Abuf, o_b, out);
}

// Round 5
// 264.177 us; speedup vs baseline: 2.3259x; 1.3990x over previous
//
#include <hip/hip_runtime.h>
#include <math.h>

// WheelMultiheadAttention on MI355X (gfx950) — v6: async LDS-staged K (wave-private, counted vmcnt),
// rz-before-PV with NT weight stores interleaved into the PV MFMA loop.
// B=2 T=2048 C=1024 H=16 D=64. Outputs: out [2,2048,1024] f32 then weights [2,16,2048,2048] f32.

typedef _Float16 f16;
typedef _Float16 f16x2 __attribute__((ext_vector_type(2)));
typedef _Float16 f16x4 __attribute__((ext_vector_type(4)));
typedef _Float16 f16x8 __attribute__((ext_vector_type(8)));
typedef float  f32x2  __attribute__((ext_vector_type(2)));
typedef float  f32x4  __attribute__((ext_vector_type(4)));

#define MFMAH(a, b, c)  __builtin_amdgcn_mfma_f32_16x16x32_f16((a), (b), (c), 0, 0, 0)

__device__ __forceinline__ void gload16(void* lds, const void* g) {
  __builtin_amdgcn_global_load_lds((__attribute__((address_space(1))) void*)(g),
                                   (__attribute__((address_space(3))) void*)(lds),
                                   16, 0, 0);
}

// ---------------- fused f32 -> f16 convert (query|key|value|q_w|k_w|v_w|o_w into one buffer) ----
__global__ __launch_bounds__(256) void conv_f16(const float* __restrict__ q, const float* __restrict__ k,
                                                const float* __restrict__ v, const float* __restrict__ qw,
                                                const float* __restrict__ kw, const float* __restrict__ vw,
                                                const float* __restrict__ ow, f16* __restrict__ xf) {
  long long i = ((long long)blockIdx.x * 256 + threadIdx.x) * 4;
  const float* src;
  long long off;
  if (i < 4194304)       { src = q;  off = 0; }
  else if (i < 8388608)  { src = k;  off = 4194304; }
  else if (i < 12582912) { src = v;  off = 8388608; }
  else if (i < 13631488) { src = qw; off = 12582912; }
  else if (i < 14680064) { src = kw; off = 13631488; }
  else if (i < 15728640) { src = vw; off = 14680064; }
  else                   { src = ow; off = 15728640; }
  f32x4 val = *(const f32x4*)(src + (i - off));
  f16x4 h;
#pragma unroll
  for (int r = 0; r < 4; ++r) h[r] = (f16)val[r];
  *(f16x4*)(xf + i) = h;
}

// ---------------- shared GEMM helpers (128x128 tile, K-step 32, stride-1024 sources) ----
__device__ __forceinline__ void stage_tile(f16* lds, const f16* g, int row0, int kc, int tid) {
#pragma unroll
  for (int j = 0; j < 2; ++j) {
    int chunk = j * 256 + tid;
    int r = chunk >> 2, cpos = chunk & 3;
    int csrc = cpos ^ ((r >> 1) & 3);
    gload16((char*)lds + chunk * 16,
            (const char*)(g + (size_t)(row0 + r) * 1024 + kc) + csrc * 16);
  }
}

__device__ __forceinline__ f16x8 frag_ld(const f16* lds, int row, int g) {
  int pos = g ^ ((row >> 1) & 3);
  return *(const f16x8*)((const char*)lds + row * 64 + pos * 16);
}

// K-loop core: acc[fm][fn] += A[o0+..][:] . X[t0+..][:] over K=1024
__device__ __forceinline__ void gemm_core(const f16* A, const f16* X, int o0, int t0, int tid,
                                          f16* sA, f16* sB, f32x4 acc[4][4]) {
  int wid = tid >> 6, lane = tid & 63;
  int wm = wid >> 1, wn = wid & 1, g = lane >> 4, r15 = lane & 15;
  for (int kc = 0; kc < 1024; kc += 32) {
    __syncthreads();
    stage_tile(sA, A, o0, kc, tid);
    stage_tile(sB, X, t0, kc, tid);
    __syncthreads();
    f16x8 a[4], x[4];
#pragma unroll
    for (int f = 0; f < 4; ++f) {
      a[f] = frag_ld(sA, wm * 64 + f * 16 + r15, g);
      x[f] = frag_ld(sB, wn * 64 + f * 16 + r15, g);
    }
#pragma unroll
    for (int fm = 0; fm < 4; ++fm)
#pragma unroll
      for (int fn = 0; fn < 4; ++fn)
        acc[fm][fn] = MFMAH(a[fm], x[fn], acc[fm][fn]);
  }
}

// ---------------- Q/K projection (batched over blockIdx.z): Y[o][t] = W[o][:].X[t][:] + b
__global__ __launch_bounds__(256) void gemm_qk(const f16* __restrict__ xf,
                                               const float* __restrict__ q_b, const float* __restrict__ k_b,
                                               f16* __restrict__ Qf, f16* __restrict__ Kf) {
  __shared__ f16 sA[4096], sB[4096];
  int z = blockIdx.z;
  const f16* A = xf + (z ? 13631488 : 12582912);
  const f16* X = xf + (z ? 4194304 : 0);
  const float* bias = z ? k_b : q_b;
  f16* Yf = z ? Kf : Qf;
  float scale = z ? 1.0f : 0.125f;
  int tid = threadIdx.x;
  int o0 = blockIdx.x * 128, t0 = blockIdx.y * 128;
  int wid = tid >> 6, lane = tid & 63;
  int wm = wid >> 1, wn = wid & 1, g = lane >> 4, r15 = lane & 15;
  f32x4 acc[4][4] = {};
  gemm_core(A, X, o0, t0, tid, sA, sB, acc);
#pragma unroll
  for (int fm = 0; fm < 4; ++fm)
#pragma unroll
    for (int fn = 0; fn < 4; ++fn) {
      int ob = o0 + wm * 64 + fm * 16 + 4 * g;
      int t  = t0 + wn * 64 + fn * 16 + r15;
      int bb = t >> 11, tl = t & 2047, hh = ob >> 6, dd = ob & 63;
      size_t base = (((size_t)bb * 16 + hh) * 2048 + tl) * 64 + dd;
      f16x4 vh;
#pragma unroll
      for (int r = 0; r < 4; ++r)
        vh[r] = (f16)((acc[fm][fn][r] + bias[ob + r]) * scale);
      *(f16x4*)(Yf + base) = vh;
    }
}

// ---------------- V projection: Y[t][o] = X[t][:].W[o][:] + b, slot-permuted VT2 ------
// VT2[bh][t/32][d][slot]; slot(g,j): j<4 -> k32=4g+j ; j>=4 -> k32=16+4g+(j-4)
__global__ __launch_bounds__(256) void gemm_v(const f16* __restrict__ xf,
                                              const float* __restrict__ bias, f16* __restrict__ VT2) {
  __shared__ f16 sA[4096], sB[4096];
  const f16* X = xf + 8388608;   // value
  const f16* W = xf + 14680064;  // v_w
  int tid = threadIdx.x;
  int t0 = blockIdx.x * 128, o0 = blockIdx.y * 128;
  int wid = tid >> 6, lane = tid & 63;
  int wm = wid >> 1, wn = wid & 1, g = lane >> 4, r15 = lane & 15;
  f32x4 acc[4][4] = {};
  gemm_core(X, W, t0, o0, tid, sA, sB, acc);
#pragma unroll
  for (int fm = 0; fm < 4; ++fm)
#pragma unroll
    for (int fn = 0; fn < 4; ++fn) {
      int tb = t0 + wm * 64 + fm * 16 + 4 * g;
      int o  = o0 + wn * 64 + fn * 16 + r15;
      int bb = tb >> 11, tl = tb & 2047, hh = o >> 6, dd = o & 63;
      int ch = tl >> 5, c = tl & 31;
      int slotbase = (c < 16) ? ((c >> 2) << 3) : ((((c - 16) >> 2) << 3) + 4);
      float bo = bias[o];
      f16x4 v4;
#pragma unroll
      for (int r = 0; r < 4; ++r) v4[r] = (f16)(acc[fm][fn][r] + bo);
      *(f16x4*)(VT2 + ((((size_t)bb * 16 + hh) * 64 + ch) * 64 + dd) * 32 + slotbase) = v4;
    }
}

// ---------------- O projection: Out[t][o] = A[t][:].o_w[o][:] + b, f32 ----------------
__global__ __launch_bounds__(256) void gemm_o(const f16* __restrict__ xf, const f16* __restrict__ Abuf,
                                              const float* __restrict__ o_b, float* __restrict__ OutF) {
  __shared__ f16 sA[4096], sB[4096];
  const f16* A = xf + 15728640;  // o_w
  int tid = threadIdx.x;
  int o0 = blockIdx.x * 128, t0 = blockIdx.y * 128;
  int wid = tid >> 6, lane = tid & 63;
  int wm = wid >> 1, wn = wid & 1, g = lane >> 4, r15 = lane & 15;
  f32x4 acc[4][4] = {};
  gemm_core(A, Abuf, o0, t0, tid, sA, sB, acc);
#pragma unroll
  for (int fm = 0; fm < 4; ++fm)
#pragma unroll
    for (int fn = 0; fn < 4; ++fn) {
      int ob = o0 + wm * 64 + fm * 16 + 4 * g;
      int t  = t0 + wn * 64 + fn * 16 + r15;
      f32x4 v;
#pragma unroll
      for (int r = 0; r < 4; ++r) v[r] = acc[fm][fn][r] + o_b[ob + r];
      *(f32x4*)(OutF + (size_t)t * 1024 + ob) = v;
    }
}

// ---------------- fused attention (v6) ----------------
// 1 block = (b, h, 16 q-rows), 512 threads (8 waves). Wave w owns k in [256w, 256w+256).
// Phase 1: K staged wave-private LDS (double-buffered, global_load_lds, counted vmcnt).
// Then rowsum -> rz; Phase 2: PV with NT weight stores interleaved; Phase 3: cross-wave reduce.
__global__ __launch_bounds__(512, 4) void attn_kernel(
    const f16* __restrict__ Qf, const f16* __restrict__ Kf,
    const f16* __restrict__ VT2, const int* __restrict__ mask,
    float* __restrict__ wout, f16* __restrict__ Abuf) {
  __shared__ f16 kstage[8][2][1024];  // per-wave dbuf K tile (16 k x 64 d f16 = 2 KB), 32 KB
  __shared__ float pvbuf[8 * 1088];   // [wave][q][68-padded d] partials, 34.8 KB
  __shared__ float ps[128];           // row-sum partials [q][wave]
  __shared__ float rz[16];
  int tid = threadIdx.x;
  int wid = tid >> 6, lane = tid & 63;
  int g = lane >> 4, r15 = lane & 15;
  int qt = blockIdx.x & 127, bh = blockIdx.x >> 7;
  int b = bh >> 4, h = bh & 15;
  int q0 = qt * 16;

  // Q fragments (B-operand: col = q = lane&15). 1/8 scale folded into Qf.
  const f16* qp = Qf + ((size_t)bh * 2048 + q0 + r15) * 64 + 8 * g;
  f16x8 qh0 = *(const f16x8*)(qp);
  f16x8 qh1 = *(const f16x8*)(qp + 32);

  // pack this lane's 64 mask bits (k = wid*256 + s*16 + 4g + r) -> bit 4s+r
  const int* mp = mask + b * 2048 + wid * 256 + 4 * g;
  unsigned long long mb = 0;
#pragma unroll
  for (int t = 0; t < 16; ++t) {
    int4 ma = *(const int4*)(mp + t * 16);
    mb |= ((ma.x ? 1ull : 0ull) << (4 * t)) | ((ma.y ? 1ull : 0ull) << (4 * t + 1)) |
          ((ma.z ? 1ull : 0ull) << (4 * t + 2)) | ((ma.w ? 1ull : 0ull) << (4 * t + 3));
  }

  // ---- phase 1: swapped QK^T with async-LDS K staging ----
  // K tile s: rows k = wid*256 + s*16 + r (r=0..15), d=0..63, LDS [16][8 chunks of 16B],
  // chunk XOR-swizzled by row&7 (source-side pre-swizzle; gload writes lane-linear).
  f16* kb0 = &kstage[wid][0][0];
  f16* kb1 = &kstage[wid][1][0];
  // per-lane global source for staging: inst A covers rows 0..7, inst B rows 8..15
  const f16* ksrcA = Kf + ((size_t)bh * 2048 + wid * 256 + (lane >> 3)) * 64 +
                     (((lane & 7) ^ ((lane >> 3) & 7)) * 8);
  const f16* ksrcB = ksrcA + 8 * 64;

  // prologue: issue tiles 0 and 1
  gload16(kb0, ksrcA);
  gload16(kb0 + 512, ksrcB);
  gload16(kb1, ksrcA + 1024);
  gload16(kb1 + 512, ksrcB + 1024);

  float psum = 0.f;
  f16x4 p16[16];
  int key = r15 & 7;
#pragma unroll
  for (int s = 0; s < 16; ++s) {
    if (s < 15) {
      asm volatile("s_waitcnt vmcnt(2)" ::: "memory");  // tile s staged
    } else {
      asm volatile("s_waitcnt vmcnt(0)" ::: "memory");
    }
    const f16* kt = (s & 1) ? kb1 : kb0;
    f16x8 c0 = *(const f16x8*)(kt + r15 * 64 + ((g ^ key) * 8));
    f16x8 c1 = *(const f16x8*)(kt + r15 * 64 + (((g + 4) ^ key) * 8));
    asm volatile("s_waitcnt lgkmcnt(0)" ::: "memory");  // frags in regs; buffer reusable
    if (s < 14) {  // issue tile s+2 into buf (s&1)
      f16* nb = (s & 1) ? kb1 : kb0;
      gload16(nb, ksrcA + (s + 2) * 1024);
      gload16(nb + 512, ksrcB + (s + 2) * 1024);
    }
    f32x4 sc = {0.f, 0.f, 0.f, 0.f};
    sc = MFMAH(c0, qh0, sc);   // A = K rows (k), B = Q (cols q)
    sc = MFMAH(c1, qh1, sc);
    f16x4 pk;
#pragma unroll
    for (int r = 0; r < 4; ++r) {
      float e = ((mb >> (4 * s + r)) & 1) ? 0.f : __expf(sc[r]);
      psum += e;
      pk[r] = (f16)e;
    }
    p16[s] = pk;
  }

  // in-wave row-sum reduce across g (lanes sharing q=r15)
  psum += __shfl_xor(psum, 16);
  psum += __shfl_xor(psum, 32);
  if (lane < 16) ps[lane * 8 + wid] = psum;
  __syncthreads();

  // finalize row sums -> rz (wheel: z==0 -> 0)
  if (tid < 128) {
    float z = ps[tid];
#pragma unroll
    for (int m = 1; m <= 4; m <<= 1) z += __shfl_xor(z, m);
    if ((tid & 7) == 0) rz[tid >> 3] = (z > 0.f) ? 1.0f / z : 0.0f;
  }
  __syncthreads();

  // ---- phase 2: PV (A = packed P regs, B = slot-permuted VT2) with NT stores interleaved ----
  f32x4 acc[4] = {};
  {
    float rzv = rz[r15];
    float* wb = wout + ((size_t)bh * 2048 + q0 + r15) * 2048 + wid * 256 + 4 * g;
    const f16* vb = VT2 + (((size_t)bh * 64 + wid * 8) * 64 + r15) * 32 + g * 8;
    f16x8 v0 = *(const f16x8*)(vb);
    f16x8 v1 = *(const f16x8*)(vb + 512);
    f16x8 v2 = *(const f16x8*)(vb + 1024);
    f16x8 v3 = *(const f16x8*)(vb + 1536);
#pragma unroll
    for (int t = 0; t < 8; ++t) {
      f16x8 n0, n1, n2, n3;
      if (t < 7) {
        const f16* nvb = vb + (t + 1) * 2048;
        n0 = *(const f16x8*)(nvb);
        n1 = *(const f16x8*)(nvb + 512);
        n2 = *(const f16x8*)(nvb + 1024);
        n3 = *(const f16x8*)(nvb + 1536);
      }
      // weight stores for s = 2t, 2t+1 (overlap with MFMAs below)
#pragma unroll
      for (int u = 0; u < 2; ++u) {
        int s = 2 * t + u;
        f16x4 pk = p16[s];
        f32x4 wv;
#pragma unroll
        for (int r = 0; r < 4; ++r) wv[r] = (float)pk[r] * rzv;
        __builtin_nontemporal_store(wv, (f32x4*)(wb + s * 16));
      }
      f16x8 af = __builtin_shufflevector(p16[2 * t], p16[2 * t + 1], 0, 1, 2, 3, 4, 5, 6, 7);
      acc[0] = MFMAH(af, v0, acc[0]);
      acc[1] = MFMAH(af, v1, acc[1]);
      acc[2] = MFMAH(af, v2, acc[2]);
      acc[3] = MFMAH(af, v3, acc[3]);
      v0 = n0; v1 = n1; v2 = n2; v3 = n3;
    }
#pragma unroll
    for (int dt = 0; dt < 4; ++dt)
#pragma unroll
      for (int r = 0; r < 4; ++r)
        pvbuf[wid * 1088 + (4 * g + r) * 68 + dt * 16 + r15] = acc[dt][r];
  }
  __syncthreads();

  // ---- phase 3: cross-wave PV reduce -> Abuf (f16 [B,T,C]) ----
  {
    int q = tid >> 5, d = (tid & 31) * 2;
    float a0 = 0.f, a1 = 0.f;
#pragma unroll
    for (int w8 = 0; w8 < 8; ++w8) {
      f32x2 v = *(const f32x2*)&pvbuf[w8 * 1088 + q * 68 + d];
      a0 += v[0];
      a1 += v[1];
    }
    float rzq = rz[q];
    f16x2 o2 = {(f16)(a0 * rzq), (f16)(a1 * rzq)};
    *(f16x2*)(Abuf + ((size_t)b * 2048 + q0 + q) * 1024 + h * 64 + d) = o2;
  }
}

extern "C" void kernel_launch(void* const* d_in, const int* in_sizes, int n_in,
                              void* d_out, int out_size, void* d_ws, size_t ws_size,
                              hipStream_t stream) {
  const float* query = (const float*)d_in[0];
  const float* key_i = (const float*)d_in[1];
  const float* value = (const float*)d_in[2];
  const float* q_w = (const float*)d_in[3];
  const float* q_b = (const float*)d_in[4];
  const float* k_w = (const float*)d_in[5];
  const float* k_b = (const float*)d_in[6];
  const float* v_w = (const float*)d_in[7];
  const float* v_b = (const float*)d_in[8];
  const float* o_w = (const float*)d_in[9];
  const float* o_b = (const float*)d_in[10];
  const int* mask = (const int*)d_in[11];
  float* out = (float*)d_out;
  float* wout = out + 4194304;  // weights output region

  // ws: xf f16[16777216] (33.6MB) | Qf f16[4194304] | Kf f16[4194304]
  const size_t XFB = 16777216ull * 2;
  const size_t QB = 4194304ull * 2;
  if (ws_size < XFB + 2 * QB) return;
  f16* xf = (f16*)d_ws;
  f16* Qf = (f16*)((char*)d_ws + XFB);
  f16* Kf = (f16*)((char*)d_ws + XFB + QB);
  f16* VT2 = xf;             // reuse query slot (dead after gemm_qk)
  f16* Abuf = xf + 4194304;  // reuse key slot (dead after gemm_qk)

  conv_f16<<<16384, 256, 0, stream>>>(query, key_i, value, q_w, k_w, v_w, o_w, xf);
  gemm_qk<<<dim3(8, 32, 2), 256, 0, stream>>>(xf, q_b, k_b, Qf, Kf);
  gemm_v<<<dim3(32, 8), 256, 0, stream>>>(xf, v_b, VT2);
  attn_kernel<<<4096, 512, 0, stream>>>(Qf, Kf, VT2, mask, wout, Abuf);
  gemm_o<<<dim3(8, 32), 256, 0, stream>>>(xf, Abuf, o_b, out);
}